// Round 6
// baseline (1016.836 us; speedup 1.0000x reference)
//
#include <hip/hip_runtime.h>

// RegressiveAutoEncoder B=2048,T=512,F=8,H=128 — MFMA v9 (VALU diet #2).
// v8 measured 1005us: VALU 53.5% + MFMA 32% = 85.5% issue-occupied at
// 2 waves/SIMD -> VALU-issue-bound. v9 cuts VALU ops, structure unchanged:
//  (1) U/W/bias pre-scaled by log2e -> gates arrive in exp2 domain; v_exp_f32
//      is natively 2^x, so every __expf's hidden v_mul disappears. cst kept
//      in scaled domain; tanh(g)'s log2e factor folded into fma constants.
//  (2) activation block rewritten as float2 (two row-streams packed) ->
//      v_pk_mul/add/fma_f32; exp/rcp remain scalar per component.
//  (3) hi/lo splits via v_cvt_pk_bf16_f32 (T12): 1 cvt_pk(hi pair) +
//      unpack + pk-sub + 1 cvt_pk(lo pair). RTNE hi (was trunc) - residual
//      still in lo, precision equal or better. x-chunk writes become b32.
// Kept from v8: decoder rotation (dense+next-h-partial MFMAs issue over the
// y epilogue VALU), encoder Ax-first chain, lgkm-only barrier, XS=40 rows,
// 16-step x chunks (load@t+2/write@t+1, xv held ACROSS steps), probe-based
// pair_fold row assignment, bias-as-C-operand, 3-term x/y rows, 0.5x bias.

namespace {

typedef __attribute__((ext_vector_type(8))) short bf16x8;
typedef __attribute__((ext_vector_type(4))) float f32x4;
typedef __attribute__((ext_vector_type(2))) unsigned int uint2v;
typedef __attribute__((ext_vector_type(4))) unsigned int uint4v;
typedef __attribute__((ext_vector_type(2))) float float2v;

constexpr int T = 512, F = 8, H = 128, G4 = 512, NTH = 512;
constexpr int HS = 136;  // hb row stride in shorts (272B, b128-aligned)
constexpr int XS = 40;   // xp/xq row stride in shorts (80B)
constexpr int CS = 16;   // encoder x chunk length (timesteps)
constexpr float L2E = 1.4426950408889634f;

struct __align__(16) Smem {
  unsigned short hb[2][16][HS];      // rows 0..7 h_hi, 8..15 h_lo; dbuf by parity
  unsigned short xp[2][16][XS];      // decoder feedback y; dbuf by parity
  unsigned short xq[2][CS][16][XS];  // encoder pre-split x chunks; dbuf by chunk
};

__device__ __forceinline__ float rcpf(float v) { return __builtin_amdgcn_rcpf(v); }

// native exp2 (v_exp_f32 IS 2^x); exp2m computes 2^-x via src modifier
__device__ __forceinline__ float exp2p(float x) { float r; asm("v_exp_f32 %0, %1" : "=v"(r) : "v"(x)); return r; }
__device__ __forceinline__ float exp2m(float x) { float r; asm("v_exp_f32_e64 %0, -%1" : "=v"(r) : "v"(x)); return r; }

// packed bf16 convert: dst[15:0]=bf16(a), dst[31:16]=bf16(b), RTNE
__device__ __forceinline__ unsigned cvt_pk_bf16(float a, float b) {
  unsigned r; asm("v_cvt_pk_bf16_f32 %0, %1, %2" : "=v"(r) : "v"(a), "v"(b)); return r;
}
// split a float2 into packed-hi (RTNE) and packed-lo (residual, RTNE)
__device__ __forceinline__ void split2_pk(float2v h, unsigned& hpk, unsigned& lpk) {
  hpk = cvt_pk_bf16(h[0], h[1]);
  float2v hif = { __uint_as_float(hpk << 16), __uint_as_float(hpk & 0xFFFF0000u) };
  float2v lo = h - hif;
  lpk = cvt_pk_bf16(lo[0], lo[1]);
}

__device__ __forceinline__ unsigned short bf_rtn(float v) {
  unsigned u = __float_as_uint(v);
  return (unsigned short)((u + 0x7FFFu + ((u >> 16) & 1u)) >> 16);
}
__device__ __forceinline__ void split_tr(float v, unsigned short& hi, unsigned short& lo) {
  unsigned u = __float_as_uint(v);
  hi = (unsigned short)(u >> 16);
  lo = bf_rtn(v - __uint_as_float(u & 0xFFFF0000u));
}

// scaled-domain gates (z' = log2e * z_true):
// sigmoid_true(z) = 1/(1+2^-z')
__device__ __forceinline__ float2v sigm2(float2v z) {
  float2v d = { exp2m(z[0]) + 1.f, exp2m(z[1]) + 1.f };
  return (float2v){ rcpf(d[0]), rcpf(d[1]) };
}
// log2e * tanh_true(z): t = 1/(2^(2z')+1); L2E - 2*L2E*t
__device__ __forceinline__ float2v gtanh2(float2v z) {
  float2v zz = z + z;
  float2v d = { exp2p(zz[0]) + 1.f, exp2p(zz[1]) + 1.f };
  return (float2v){ fmaf(rcpf(d[0]), -2.f * L2E, L2E), fmaf(rcpf(d[1]), -2.f * L2E, L2E) };
}
// tanh_true(c_true) from scaled c' = log2e*c_true: 1 - 2/(2^(2c')+1)
__device__ __forceinline__ float2v ttanh2(float2v c) {
  float2v cc = c + c;
  float2v d = { exp2p(cc[0]) + 1.f, exp2p(cc[1]) + 1.f };
  return (float2v){ fmaf(rcpf(d[0]), -2.f, 1.f), fmaf(rcpf(d[1]), -2.f, 1.f) };
}

// Pair-fold: one half-wave gets fold32(a)=a[l]+a[l^32], the other fold32(b);
// which half gets which is probed once and baked into r0.
__device__ __forceinline__ float pair_fold(float a, float b) {
  uint2v r = __builtin_amdgcn_permlane32_swap(__float_as_uint(a), __float_as_uint(b), false, false);
  return __uint_as_float(r[0]) + __uint_as_float(r[1]);
}

// Barrier draining only LDS (lgkm); outstanding global ops not drained.
__device__ __forceinline__ void bar_lgkm() {
  __asm__ __volatile__("s_waitcnt lgkmcnt(0)" ::: "memory");
  __builtin_amdgcn_s_barrier();
  __asm__ __volatile__("" ::: "memory");
}

__global__ __launch_bounds__(NTH, 2)
void rae_v9(const float* __restrict__ x,
            const float* __restrict__ Wenc, const float* __restrict__ Uenc, const float* __restrict__ benc,
            const float* __restrict__ Wdec, const float* __restrict__ Udec, const float* __restrict__ bdec,
            const float* __restrict__ Wout, const float* __restrict__ boutg,
            float* __restrict__ out)
{
  __shared__ Smem s;
  const int tid = threadIdx.x, lane = tid & 63, w = tid >> 6;
  const int q = lane >> 4, n = lane & 15;
  const long gb = (long)blockIdx.x * 8;

  {  // vectorized zero of all LDS (zeros double as the K-padding regions)
    uint4v z4 = {0u, 0u, 0u, 0u};
#pragma unroll 4
    for (int i = tid; i < (int)(sizeof(Smem) / 16); i += NTH)
      ((uint4v*)&s)[i] = z4;
  }
  __syncthreads();  // zero pass must complete before any staging

  // encoder x staging: 512 thr = 16 steps x 8 rows x 4 float2.
  const int sfp = tid & 3, srow = (tid >> 2) & 7, sts = tid >> 5;
  const long xsb = (gb + srow) * (long)(T * F) + sts * F + sfp * 2;

  {  // stage chunk 0 (steps 0..15); u32 writes (4B-aligned: 80B rows)
    float2v xv0 = *(const float2v*)&x[xsb];
    unsigned xh, xl; split2_pk(xv0, xh, xl);
    *(unsigned*)&s.xq[0][sts][srow][sfp * 2] = xh;
    *(unsigned*)&s.xq[0][sts][srow + 8][sfp * 2] = xl;
    *(unsigned*)&s.xq[0][sts][srow + 8][8 + sfp * 2] = xh;
  }

  // Wout fragments (UNSCALED): N-cols 0..7 = Wout_hi, 8..15 = Wout_lo
  bf16x8 Bw[4];
#pragma unroll
  for (int kt = 0; kt < 4; ++kt) {
    bf16x8 bw;
#pragma unroll
    for (int j = 0; j < 8; ++j) {
      unsigned short hv, lv; split_tr(Wout[(kt * 32 + q * 8 + j) * F + (n & 7)], hv, lv);
      bw[j] = (short)((n < 8) ? hv : lv);
    }
    Bw[kt] = bw;
  }
  const float boutr = boutg[n & 7];
  float2v cst2 = {0.f, 0.f};  // cell state in log2e-scaled domain
  __syncthreads();

  // Convention probe -> row offset owned by this lane's pair_fold outputs.
  const float probe = pair_fold(0.0f, 1.0f);
  const int r0 = ((lane & 31) >> 4) * 4 + (int)probe;
  const int cc = w * 16 + n;

  bf16x8 A[4], Ax;
  {
    bf16x8 zz = {0, 0, 0, 0, 0, 0, 0, 0};
#pragma unroll
    for (int kt = 0; kt < 4; ++kt) A[kt] = zz;
    Ax = zz;
  }

  bf16x8 B1[5][4];
  f32x4 bias4[4];
  const f32x4 zero4 = {0.f, 0.f, 0.f, 0.f};

  // ---- weight preload (per phase); U/W/bias pre-scaled by log2e ----
  auto preload = [&](const float* U, const float* W, const float* bi) {
#pragma unroll
    for (int kt = 0; kt < 5; ++kt)
#pragma unroll
      for (int g = 0; g < 4; ++g) {
        const int col = g * 128 + w * 16 + n;
        bf16x8 b1;
#pragma unroll
        for (int j = 0; j < 8; ++j) {
          unsigned short v = 0;
          if (kt < 4) {
            v = bf_rtn(L2E * U[(kt * 32 + q * 8 + j) * G4 + col]);
          } else {
            const int kk = q * 8 + j;
            unsigned short hv, lv;
            if (kk < 8)       { split_tr(L2E * W[kk * G4 + col], hv, lv); v = hv; }
            else if (kk < 16) { split_tr(L2E * W[(kk - 8) * G4 + col], hv, lv); v = lv; }
          }
          b1[j] = (short)v;
        }
        B1[kt][g] = b1;
      }
#pragma unroll
    for (int g = 0; g < 4; ++g) {
      const float b = 0.5f * L2E * bi[g * 128 + w * 16 + n];
      bias4[g] = f32x4{b, b, b, b};
    }
  };

  // ---- fold + LSTM cell (packed float2 streams) + h store ----
  auto activ_store = [&](f32x4 (&acc)[4], int slot) {
    const float2v zi = { pair_fold(acc[0][0], acc[0][2]), pair_fold(acc[0][1], acc[0][3]) };
    const float2v zf = { pair_fold(acc[1][0], acc[1][2]), pair_fold(acc[1][1], acc[1][3]) };
    const float2v zg = { pair_fold(acc[2][0], acc[2][2]), pair_fold(acc[2][1], acc[2][3]) };
    const float2v zo = { pair_fold(acc[3][0], acc[3][2]), pair_fold(acc[3][1], acc[3][3]) };
    cst2 = sigm2(zf) * cst2 + sigm2(zi) * gtanh2(zg);
    const float2v hh = sigm2(zo) * ttanh2(cst2);
    unsigned hpk, lpk; split2_pk(hh, hpk, lpk);
    s.hb[slot][r0][cc]     = (unsigned short)hpk;
    s.hb[slot][r0 + 8][cc] = (unsigned short)lpk;
    s.hb[slot][r0 + 1][cc] = (unsigned short)(hpk >> 16);
    s.hb[slot][r0 + 9][cc] = (unsigned short)(lpk >> 16);
  };

  // =================== ENCODER ===================
  preload(Uenc, Wenc, benc);

  // prologue: h_{-1}=0 (A already zero); Ax = x_0 (chunk 0 staged + synced)
  Ax = *(const bf16x8*)&s.xq[0][0][n][q * 8];

  float2v xv = {0.f, 0.f};  // in-flight next-chunk x (held ACROSS steps)

#pragma unroll 2
  for (int t = 0; t < T; ++t) {
    const int pnxt = (t & 1) ^ 1;
    const bool do_load  = (((t + 2) & (CS - 1)) == 0) && (t + 2 < T);
    const bool do_write = (((t + 1) & (CS - 1)) == 0) && (t + 1 < T);
    if (do_load) xv = *(const float2v*)&x[xsb + (long)(t + 2) * F];

    // chain starts with the x-term (Ax ready immediately post-barrier)
    f32x4 acc[4];
#pragma unroll
    for (int g = 0; g < 4; ++g)
      acc[g] = __builtin_amdgcn_mfma_f32_16x16x32_bf16(Ax, B1[4][g], bias4[g], 0, 0, 0);
#pragma unroll
    for (int kt = 0; kt < 4; ++kt)
#pragma unroll
      for (int g = 0; g < 4; ++g)
        acc[g] = __builtin_amdgcn_mfma_f32_16x16x32_bf16(A[kt], B1[kt][g], acc[g], 0, 0, 0);

    activ_store(acc, pnxt);

    if (do_write) {
      const int cb = ((t + 1) >> 4) & 1;
      unsigned xh, xl; split2_pk(xv, xh, xl);
      *(unsigned*)&s.xq[cb][sts][srow][sfp * 2] = xh;
      *(unsigned*)&s.xq[cb][sts][srow + 8][sfp * 2] = xl;
      *(unsigned*)&s.xq[cb][sts][srow + 8][8 + sfp * 2] = xh;
    }

    bar_lgkm();

    // reads for step t+1: Ax FIRST (first MFMA next iter waits lgkmcnt(4))
    const int tn = t + 1;  // tn==T reads stale chunk-0 word: harmless, unused
    Ax = *(const bf16x8*)&s.xq[(tn >> 4) & 1][tn & (CS - 1)][n][q * 8];
#pragma unroll
    for (int kt = 0; kt < 4; ++kt)
      A[kt] = *(const bf16x8*)&s.hb[pnxt][n][kt * 32 + q * 8];
  }

  // =================== DECODER (rotated) ===================
  preload(Udec, Wdec, bdec);

  if (tid < 64) {  // stage y_{-1} = x[:,T-1,:] into xp[1] (slot (0-1)&1)
    unsigned short hv, lv;
    split_tr(x[(gb + (tid >> 3)) * (long)(T * F) + (T - 1) * F + (tid & 7)], hv, lv);
    s.xp[1][tid >> 3][tid & 7] = hv;
    s.xp[1][(tid >> 3) + 8][tid & 7] = lv;
    s.xp[1][(tid >> 3) + 8][(tid & 7) + 8] = hv;
  }
  __syncthreads();

  // prologue: A still holds h_enc (encoder's final bottom-read of hb[0]).
  f32x4 hacc[4];
#pragma unroll
  for (int g = 0; g < 4; ++g)
    hacc[g] = __builtin_amdgcn_mfma_f32_16x16x32_bf16(A[0], B1[0][g], bias4[g], 0, 0, 0);
#pragma unroll
  for (int kt = 1; kt < 4; ++kt)
#pragma unroll
    for (int g = 0; g < 4; ++g)
      hacc[g] = __builtin_amdgcn_mfma_f32_16x16x32_bf16(A[kt], B1[kt][g], hacc[g], 0, 0, 0);
  Ax = *(const bf16x8*)&s.xp[1][n][q * 8];

  // per-lane output row pointers (rows r0 and r0+1, col n; valid for n<8)
  float* o0 = out + ((gb + r0) * (long)T) * F + n;
  float* o1 = o0 + (long)T * F;

#pragma unroll 2
  for (int t = 0; t < T; ++t) {
    const int wA = (t & 1) ^ 1;  // hb slot for h_t

    // finish LSTM: acc = hacc + Ax*B1[4]  (4 MFMA)
    f32x4 acc[4];
#pragma unroll
    for (int g = 0; g < 4; ++g)
      acc[g] = __builtin_amdgcn_mfma_f32_16x16x32_bf16(Ax, B1[4][g], hacc[g], 0, 0, 0);

    activ_store(acc, wA);

    bar_lgkm();

#pragma unroll
    for (int kt = 0; kt < 4; ++kt)
      A[kt] = *(const bf16x8*)&s.hb[wA][n][kt * 32 + q * 8];

    // dense first (y_t on the feedback critical path) ...
    f32x4 ay = __builtin_amdgcn_mfma_f32_16x16x32_bf16(A[0], Bw[0], zero4, 0, 0, 0);
#pragma unroll
    for (int kt = 1; kt < 4; ++kt)
      ay = __builtin_amdgcn_mfma_f32_16x16x32_bf16(A[kt], Bw[kt], ay, 0, 0, 0);

    // ... then next-step h-partial (16 MFMA, independent of y_t) issues
    // while the y epilogue below runs on VALU.
#pragma unroll
    for (int g = 0; g < 4; ++g)
      hacc[g] = __builtin_amdgcn_mfma_f32_16x16x32_bf16(A[0], B1[0][g], bias4[g], 0, 0, 0);
#pragma unroll
    for (int kt = 1; kt < 4; ++kt)
#pragma unroll
      for (int g = 0; g < 4; ++g)
        hacc[g] = __builtin_amdgcn_mfma_f32_16x16x32_bf16(A[kt], B1[kt][g], hacc[g], 0, 0, 0);

    // y epilogue (packed): fold32 and shfl8 commute -> pf first, one sh8 each
    const float2v sy = { pair_fold(ay[0], ay[2]), pair_fold(ay[1], ay[3]) };
    const float2v so = { __shfl_xor(sy[0], 8, 64), __shfl_xor(sy[1], 8, 64) };
    const float2v yraw = sy + so + (float2v){boutr, boutr};
    const float2v yy = { fmaxf(yraw[0], 0.f), fmaxf(yraw[1], 0.f) };  // rows r0, r0+1
    if (n < 8) {
      if (w == 0) { o0[t * F] = yy[0]; o1[t * F] = yy[1]; }
      unsigned yh, yl; split2_pk(yy, yh, yl);
      s.xp[t & 1][r0][n]         = (unsigned short)yh;
      s.xp[t & 1][r0 + 8][n]     = (unsigned short)yl;
      s.xp[t & 1][r0 + 8][n + 8] = (unsigned short)yh;
      s.xp[t & 1][r0 + 1][n]     = (unsigned short)(yh >> 16);
      s.xp[t & 1][r0 + 9][n]     = (unsigned short)(yl >> 16);
      s.xp[t & 1][r0 + 9][n + 8] = (unsigned short)(yh >> 16);
    }
    // own-wave readback (same-wave DS ordering; proven pattern since v5)
    Ax = *(const bf16x8*)&s.xp[t & 1][n][q * 8];
  }
}

} // namespace

extern "C" void kernel_launch(void* const* d_in, const int* in_sizes, int n_in,
                              void* d_out, int out_size, void* d_ws, size_t ws_size,
                              hipStream_t stream) {
  const float* x    = (const float*)d_in[0];
  const float* Wenc = (const float*)d_in[1];
  const float* Uenc = (const float*)d_in[2];
  const float* benc = (const float*)d_in[3];
  const float* Wdec = (const float*)d_in[4];
  const float* Udec = (const float*)d_in[5];
  const float* bdec = (const float*)d_in[6];
  const float* Wout = (const float*)d_in[7];
  const float* bout = (const float*)d_in[8];
  float* out = (float*)d_out;

  const int Bsz = in_sizes[0] / (T * F);  // 2048
  const int nblocks = Bsz / 8;            // 256
  rae_v9<<<dim3(nblocks), dim3(NTH), 0, stream>>>(
      x, Wenc, Uenc, benc, Wdec, Udec, bdec, Wout, bout, out);
}

// Round 7
// 990.699 us; speedup vs baseline: 1.0264x; 1.0264x over previous
//
#include <hip/hip_runtime.h>

// RegressiveAutoEncoder B=2048,T=512,F=8,H=128 — MFMA v10 (phase interleave).
// v9 falsified "VALU-issue-bound": VALU busy -19% but dur +2%. Limiter is
// phase serialization: per step all 8 waves do {MFMA burst} then {act burst}
// in lockstep -> pipes serialize (sum ~= step). v10:
//  (1) REVERT asm v_cvt_pk_bf16_f32 splits -> split_tr codegen (guide T12 /
//      m240: hand-written cvt_pk asm is -37% vs scalar; the v9 regression)
//  (2) per-gate MFMA chains with interleaved activation: f-chain, i-chain,
//      fold+sigm(f) under g-chain issue, cst2 updates under o-chain ->
//      trans-latency hides under MFMA issue (encoder analog of v8 rotation)
//  (3) s_setprio(1) around MFMA clusters (T5; waves skew between barriers)
// Kept from v9: log2e-scaled U/W/bias + native exp2 (asm, single-instr),
// packed float2 gate math, bias-as-C-operand. Kept from v8: decoder
// rotation, Ax-first reads, lgkm-only barrier, XS=40 rows, 16-step x chunks
// (load@t+2 / write@t+1, xv held ACROSS steps), probe-based pair_fold rows.

namespace {

typedef __attribute__((ext_vector_type(8))) short bf16x8;
typedef __attribute__((ext_vector_type(4))) float f32x4;
typedef __attribute__((ext_vector_type(2))) unsigned int uint2v;
typedef __attribute__((ext_vector_type(4))) unsigned int uint4v;
typedef __attribute__((ext_vector_type(2))) unsigned short ushort2v;
typedef __attribute__((ext_vector_type(2))) float float2v;

constexpr int T = 512, F = 8, H = 128, G4 = 512, NTH = 512;
constexpr int HS = 136;  // hb row stride in shorts (272B, b128-aligned)
constexpr int XS = 40;   // xp/xq row stride in shorts (80B)
constexpr int CS = 16;   // encoder x chunk length (timesteps)
constexpr float L2E = 1.4426950408889634f;

struct __align__(16) Smem {
  unsigned short hb[2][16][HS];      // rows 0..7 h_hi, 8..15 h_lo; dbuf by parity
  unsigned short xp[2][16][XS];      // decoder feedback y; dbuf by parity
  unsigned short xq[2][CS][16][XS];  // encoder pre-split x chunks; dbuf by chunk
};

__device__ __forceinline__ float rcpf(float v) { return __builtin_amdgcn_rcpf(v); }

// native exp2 (v_exp_f32 IS 2^x); exp2m computes 2^-x via src modifier
__device__ __forceinline__ float exp2p(float x) { float r; asm("v_exp_f32 %0, %1" : "=v"(r) : "v"(x)); return r; }
__device__ __forceinline__ float exp2m(float x) { float r; asm("v_exp_f32_e64 %0, -%1" : "=v"(r) : "v"(x)); return r; }

__device__ __forceinline__ unsigned short bf_rtn(float v) {
  unsigned u = __float_as_uint(v);
  return (unsigned short)((u + 0x7FFFu + ((u >> 16) & 1u)) >> 16);
}
__device__ __forceinline__ void split_tr(float v, unsigned short& hi, unsigned short& lo) {
  unsigned u = __float_as_uint(v);
  hi = (unsigned short)(u >> 16);
  lo = bf_rtn(v - __uint_as_float(u & 0xFFFF0000u));
}

// scaled-domain gates (z' = log2e * z_true):
__device__ __forceinline__ float2v sigm2(float2v z) {        // sigmoid_true
  float2v d = { exp2m(z[0]) + 1.f, exp2m(z[1]) + 1.f };
  return (float2v){ rcpf(d[0]), rcpf(d[1]) };
}
__device__ __forceinline__ float2v gtanh2(float2v z) {       // log2e * tanh_true
  float2v zz = z + z;
  float2v d = { exp2p(zz[0]) + 1.f, exp2p(zz[1]) + 1.f };
  return (float2v){ fmaf(rcpf(d[0]), -2.f * L2E, L2E), fmaf(rcpf(d[1]), -2.f * L2E, L2E) };
}
__device__ __forceinline__ float2v ttanh2(float2v c) {       // tanh_true of scaled c
  float2v cc = c + c;
  float2v d = { exp2p(cc[0]) + 1.f, exp2p(cc[1]) + 1.f };
  return (float2v){ fmaf(rcpf(d[0]), -2.f, 1.f), fmaf(rcpf(d[1]), -2.f, 1.f) };
}

// Pair-fold: one half-wave gets fold32(a)=a[l]+a[l^32], the other fold32(b);
// which half gets which is probed once and baked into r0.
__device__ __forceinline__ float pair_fold(float a, float b) {
  uint2v r = __builtin_amdgcn_permlane32_swap(__float_as_uint(a), __float_as_uint(b), false, false);
  return __uint_as_float(r[0]) + __uint_as_float(r[1]);
}
__device__ __forceinline__ float2v fold4(const f32x4& z4) {
  return (float2v){ pair_fold(z4[0], z4[2]), pair_fold(z4[1], z4[3]) };
}

// Barrier draining only LDS (lgkm); outstanding global ops not drained.
__device__ __forceinline__ void bar_lgkm() {
  __asm__ __volatile__("s_waitcnt lgkmcnt(0)" ::: "memory");
  __builtin_amdgcn_s_barrier();
  __asm__ __volatile__("" ::: "memory");
}

__global__ __launch_bounds__(NTH, 2)
void rae_v10(const float* __restrict__ x,
             const float* __restrict__ Wenc, const float* __restrict__ Uenc, const float* __restrict__ benc,
             const float* __restrict__ Wdec, const float* __restrict__ Udec, const float* __restrict__ bdec,
             const float* __restrict__ Wout, const float* __restrict__ boutg,
             float* __restrict__ out)
{
  __shared__ Smem s;
  const int tid = threadIdx.x, lane = tid & 63, w = tid >> 6;
  const int q = lane >> 4, n = lane & 15;
  const long gb = (long)blockIdx.x * 8;

  {  // vectorized zero of all LDS (zeros double as the K-padding regions)
    uint4v z4 = {0u, 0u, 0u, 0u};
#pragma unroll 4
    for (int i = tid; i < (int)(sizeof(Smem) / 16); i += NTH)
      ((uint4v*)&s)[i] = z4;
  }
  __syncthreads();  // zero pass must complete before any staging

  // encoder x staging: 512 thr = 16 steps x 8 rows x 4 float2.
  const int sfp = tid & 3, srow = (tid >> 2) & 7, sts = tid >> 5;
  const long xsb = (gb + srow) * (long)(T * F) + sts * F + sfp * 2;

  {  // stage chunk 0 (steps 0..15)
    float2v xv0 = *(const float2v*)&x[xsb];
    unsigned short h0s, l0s, h1s, l1s;
    split_tr(xv0[0], h0s, l0s); split_tr(xv0[1], h1s, l1s);
    ushort2v hh = {h0s, h1s}, ll = {l0s, l1s};
    *(ushort2v*)&s.xq[0][sts][srow][sfp * 2] = hh;
    *(ushort2v*)&s.xq[0][sts][srow + 8][sfp * 2] = ll;
    *(ushort2v*)&s.xq[0][sts][srow + 8][8 + sfp * 2] = hh;
  }

  // Wout fragments (UNSCALED): N-cols 0..7 = Wout_hi, 8..15 = Wout_lo
  bf16x8 Bw[4];
#pragma unroll
  for (int kt = 0; kt < 4; ++kt) {
    bf16x8 bw;
#pragma unroll
    for (int j = 0; j < 8; ++j) {
      unsigned short hv, lv; split_tr(Wout[(kt * 32 + q * 8 + j) * F + (n & 7)], hv, lv);
      bw[j] = (short)((n < 8) ? hv : lv);
    }
    Bw[kt] = bw;
  }
  const float boutr = boutg[n & 7];
  float2v cst2 = {0.f, 0.f};  // cell state in log2e-scaled domain
  __syncthreads();

  // Convention probe -> row offset owned by this lane's pair_fold outputs.
  const float probe = pair_fold(0.0f, 1.0f);
  const int r0 = ((lane & 31) >> 4) * 4 + (int)probe;
  const int cc = w * 16 + n;

  bf16x8 A[4], Ax;
  {
    bf16x8 zz = {0, 0, 0, 0, 0, 0, 0, 0};
#pragma unroll
    for (int kt = 0; kt < 4; ++kt) A[kt] = zz;
    Ax = zz;
  }

  bf16x8 B1[5][4];
  f32x4 bias4[4];
  const f32x4 zero4 = {0.f, 0.f, 0.f, 0.f};

  // ---- weight preload (per phase); U/W/bias pre-scaled by log2e ----
  auto preload = [&](const float* U, const float* W, const float* bi) {
#pragma unroll
    for (int kt = 0; kt < 5; ++kt)
#pragma unroll
      for (int g = 0; g < 4; ++g) {
        const int col = g * 128 + w * 16 + n;
        bf16x8 b1;
#pragma unroll
        for (int j = 0; j < 8; ++j) {
          unsigned short v = 0;
          if (kt < 4) {
            v = bf_rtn(L2E * U[(kt * 32 + q * 8 + j) * G4 + col]);
          } else {
            const int kk = q * 8 + j;
            unsigned short hv, lv;
            if (kk < 8)       { split_tr(L2E * W[kk * G4 + col], hv, lv); v = hv; }
            else if (kk < 16) { split_tr(L2E * W[(kk - 8) * G4 + col], hv, lv); v = lv; }
          }
          b1[j] = (short)v;
        }
        B1[kt][g] = b1;
      }
#pragma unroll
    for (int g = 0; g < 4; ++g) {
      const float b = 0.5f * L2E * bi[g * 128 + w * 16 + n];
      bias4[g] = f32x4{b, b, b, b};
    }
  };

  // finish activation from folded packed gates + store h (shared enc/dec)
  auto finish_store = [&](float2v sf, float2v si, float2v gg, float2v zo, int slot) {
    cst2 = sf * cst2 + si * gg;
    const float2v hh = sigm2(zo) * ttanh2(cst2);
    unsigned short hv0, lv0, hv1, lv1;
    split_tr(hh[0], hv0, lv0); split_tr(hh[1], hv1, lv1);
    s.hb[slot][r0][cc]     = hv0;  s.hb[slot][r0 + 8][cc] = lv0;
    s.hb[slot][r0 + 1][cc] = hv1;  s.hb[slot][r0 + 9][cc] = lv1;
  };

  // =================== ENCODER ===================
  preload(Uenc, Wenc, benc);

  // prologue: h_{-1}=0 (A already zero); Ax = x_0 (chunk 0 staged + synced)
  Ax = *(const bf16x8*)&s.xq[0][0][n][q * 8];

  float2v xv = {0.f, 0.f};  // in-flight next-chunk x (held ACROSS steps)

#pragma unroll 2
  for (int t = 0; t < T; ++t) {
    const int pnxt = (t & 1) ^ 1;
    const bool do_load  = (((t + 2) & (CS - 1)) == 0) && (t + 2 < T);
    const bool do_write = (((t + 1) & (CS - 1)) == 0) && (t + 1 < T);
    if (do_load) xv = *(const float2v*)&x[xsb + (long)(t + 2) * F];

    // ---- per-gate chains: f, i first; their folds/sigms interleave under
    //      the g and o chains' MFMA issue ----
    f32x4 zf4, zi4, zg4, zo4;
    __builtin_amdgcn_s_setprio(1);
    zf4 = __builtin_amdgcn_mfma_f32_16x16x32_bf16(Ax, B1[4][1], bias4[1], 0, 0, 0);
#pragma unroll
    for (int kt = 0; kt < 4; ++kt)
      zf4 = __builtin_amdgcn_mfma_f32_16x16x32_bf16(A[kt], B1[kt][1], zf4, 0, 0, 0);
    zi4 = __builtin_amdgcn_mfma_f32_16x16x32_bf16(Ax, B1[4][0], bias4[0], 0, 0, 0);
#pragma unroll
    for (int kt = 0; kt < 4; ++kt)
      zi4 = __builtin_amdgcn_mfma_f32_16x16x32_bf16(A[kt], B1[kt][0], zi4, 0, 0, 0);
    const float2v sf = sigm2(fold4(zf4));   // overlaps g-chain issue
    zg4 = __builtin_amdgcn_mfma_f32_16x16x32_bf16(Ax, B1[4][2], bias4[2], 0, 0, 0);
#pragma unroll
    for (int kt = 0; kt < 4; ++kt)
      zg4 = __builtin_amdgcn_mfma_f32_16x16x32_bf16(A[kt], B1[kt][2], zg4, 0, 0, 0);
    const float2v si = sigm2(fold4(zi4));   // overlaps o-chain issue
    zo4 = __builtin_amdgcn_mfma_f32_16x16x32_bf16(Ax, B1[4][3], bias4[3], 0, 0, 0);
#pragma unroll
    for (int kt = 0; kt < 4; ++kt)
      zo4 = __builtin_amdgcn_mfma_f32_16x16x32_bf16(A[kt], B1[kt][3], zo4, 0, 0, 0);
    __builtin_amdgcn_s_setprio(0);
    const float2v gg = gtanh2(fold4(zg4));

    finish_store(sf, si, gg, fold4(zo4), pnxt);

    if (do_write) {
      const int cb = ((t + 1) >> 4) & 1;
      unsigned short h0s, l0s, h1s, l1s;
      split_tr(xv[0], h0s, l0s); split_tr(xv[1], h1s, l1s);
      ushort2v hh = {h0s, h1s}, ll = {l0s, l1s};
      *(ushort2v*)&s.xq[cb][sts][srow][sfp * 2] = hh;
      *(ushort2v*)&s.xq[cb][sts][srow + 8][sfp * 2] = ll;
      *(ushort2v*)&s.xq[cb][sts][srow + 8][8 + sfp * 2] = hh;
    }

    bar_lgkm();

    // reads for step t+1: Ax FIRST (first MFMA next iter waits lgkmcnt(4))
    const int tn = t + 1;  // tn==T reads stale chunk-0 word: harmless, unused
    Ax = *(const bf16x8*)&s.xq[(tn >> 4) & 1][tn & (CS - 1)][n][q * 8];
#pragma unroll
    for (int kt = 0; kt < 4; ++kt)
      A[kt] = *(const bf16x8*)&s.hb[pnxt][n][kt * 32 + q * 8];
  }

  // =================== DECODER (rotated) ===================
  preload(Udec, Wdec, bdec);

  if (tid < 64) {  // stage y_{-1} = x[:,T-1,:] into xp[1] (slot (0-1)&1)
    unsigned short hv, lv;
    split_tr(x[(gb + (tid >> 3)) * (long)(T * F) + (T - 1) * F + (tid & 7)], hv, lv);
    s.xp[1][tid >> 3][tid & 7] = hv;
    s.xp[1][(tid >> 3) + 8][tid & 7] = lv;
    s.xp[1][(tid >> 3) + 8][(tid & 7) + 8] = hv;
  }
  __syncthreads();

  // prologue: A still holds h_enc (encoder's final bottom-read of hb[0]).
  f32x4 hacc[4];
#pragma unroll
  for (int g = 0; g < 4; ++g)
    hacc[g] = __builtin_amdgcn_mfma_f32_16x16x32_bf16(A[0], B1[0][g], bias4[g], 0, 0, 0);
#pragma unroll
  for (int kt = 1; kt < 4; ++kt)
#pragma unroll
    for (int g = 0; g < 4; ++g)
      hacc[g] = __builtin_amdgcn_mfma_f32_16x16x32_bf16(A[kt], B1[kt][g], hacc[g], 0, 0, 0);
  Ax = *(const bf16x8*)&s.xp[1][n][q * 8];

  // per-lane output row pointers (rows r0 and r0+1, col n; valid for n<8)
  float* o0 = out + ((gb + r0) * (long)T) * F + n;
  float* o1 = o0 + (long)T * F;

#pragma unroll 2
  for (int t = 0; t < T; ++t) {
    const int wA = (t & 1) ^ 1;  // hb slot for h_t

    // finish LSTM per gate (1 MFMA each); folds interleave under later MFMAs
    f32x4 zf4 = __builtin_amdgcn_mfma_f32_16x16x32_bf16(Ax, B1[4][1], hacc[1], 0, 0, 0);
    f32x4 zi4 = __builtin_amdgcn_mfma_f32_16x16x32_bf16(Ax, B1[4][0], hacc[0], 0, 0, 0);
    const float2v sf = sigm2(fold4(zf4));
    f32x4 zg4 = __builtin_amdgcn_mfma_f32_16x16x32_bf16(Ax, B1[4][2], hacc[2], 0, 0, 0);
    const float2v si = sigm2(fold4(zi4));
    f32x4 zo4 = __builtin_amdgcn_mfma_f32_16x16x32_bf16(Ax, B1[4][3], hacc[3], 0, 0, 0);
    const float2v gg = gtanh2(fold4(zg4));

    finish_store(sf, si, gg, fold4(zo4), wA);

    bar_lgkm();

#pragma unroll
    for (int kt = 0; kt < 4; ++kt)
      A[kt] = *(const bf16x8*)&s.hb[wA][n][kt * 32 + q * 8];

    // dense first (y_t on the feedback critical path) ...
    __builtin_amdgcn_s_setprio(1);
    f32x4 ay = __builtin_amdgcn_mfma_f32_16x16x32_bf16(A[0], Bw[0], zero4, 0, 0, 0);
#pragma unroll
    for (int kt = 1; kt < 4; ++kt)
      ay = __builtin_amdgcn_mfma_f32_16x16x32_bf16(A[kt], Bw[kt], ay, 0, 0, 0);

    // ... then next-step h-partial (16 MFMA, independent of y_t) issues
    // while the y epilogue below runs on VALU.
#pragma unroll
    for (int g = 0; g < 4; ++g)
      hacc[g] = __builtin_amdgcn_mfma_f32_16x16x32_bf16(A[0], B1[0][g], bias4[g], 0, 0, 0);
#pragma unroll
    for (int kt = 1; kt < 4; ++kt)
#pragma unroll
      for (int g = 0; g < 4; ++g)
        hacc[g] = __builtin_amdgcn_mfma_f32_16x16x32_bf16(A[kt], B1[kt][g], hacc[g], 0, 0, 0);
    __builtin_amdgcn_s_setprio(0);

    // y epilogue: fold32 and shfl8 commute -> pf first, single sh8 each
    const float2v sy = { pair_fold(ay[0], ay[2]), pair_fold(ay[1], ay[3]) };
    const float2v so = { __shfl_xor(sy[0], 8, 64), __shfl_xor(sy[1], 8, 64) };
    const float2v yraw = sy + so + (float2v){boutr, boutr};
    const float y0 = fmaxf(yraw[0], 0.f), y1 = fmaxf(yraw[1], 0.f);  // rows r0, r0+1
    if (n < 8) {
      if (w == 0) { o0[t * F] = y0; o1[t * F] = y1; }
      unsigned short hv, lv;
      split_tr(y0, hv, lv);
      s.xp[t & 1][r0][n]         = hv;
      s.xp[t & 1][r0 + 8][n]     = lv;
      s.xp[t & 1][r0 + 8][n + 8] = hv;
      split_tr(y1, hv, lv);
      s.xp[t & 1][r0 + 1][n]     = hv;
      s.xp[t & 1][r0 + 9][n]     = lv;
      s.xp[t & 1][r0 + 9][n + 8] = hv;
    }
    // own-wave readback (same-wave DS ordering; proven pattern since v5)
    Ax = *(const bf16x8*)&s.xp[t & 1][n][q * 8];
  }
}

} // namespace

extern "C" void kernel_launch(void* const* d_in, const int* in_sizes, int n_in,
                              void* d_out, int out_size, void* d_ws, size_t ws_size,
                              hipStream_t stream) {
  const float* x    = (const float*)d_in[0];
  const float* Wenc = (const float*)d_in[1];
  const float* Uenc = (const float*)d_in[2];
  const float* benc = (const float*)d_in[3];
  const float* Wdec = (const float*)d_in[4];
  const float* Udec = (const float*)d_in[5];
  const float* bdec = (const float*)d_in[6];
  const float* Wout = (const float*)d_in[7];
  const float* bout = (const float*)d_in[8];
  float* out = (float*)d_out;

  const int Bsz = in_sizes[0] / (T * F);  // 2048
  const int nblocks = Bsz / 8;            // 256
  rae_v10<<<dim3(nblocks), dim3(NTH), 0, stream>>>(
      x, Wenc, Uenc, benc, Wdec, Udec, bdec, Wout, bout, out);
}

// Round 8
// 980.976 us; speedup vs baseline: 1.0366x; 1.0099x over previous
//
#include <hip/hip_runtime.h>

// RegressiveAutoEncoder B=2048,T=512,F=8,H=128 — MFMA v11 (encoder rotation).
// v8/v9/v10 plateau ~990-1016us: barrier-locked waves can't cross-overlap
// pipes; only WITHIN-wave rotation moved the needle (v8 decoder +7%).
// v11 gives the ENCODER its rotation:
//  (1) pre-barrier x-term: px[g] = bias + x_{t+1}*W (4 MFMA) computed BEFORE
//      the barrier, overlapping the activation tail on the MFMA pipe; the
//      post-barrier critical path loses the Ax read + 4 MFMA. Requires
//      staging shift: chunk load@ (t+3)%16==0, write@ (t+2)%16==0 -> the
//      pre-bar Ax read targets the buffer NOT being written (verified all t;
//      boundary tn%16==0 reads a chunk written before the previous barrier).
//  (2) gg/cst2/ttanh2 hoisted between g-chain and o-chain -> post-o tail is
//      only fold+sigm+mul+split.
//  (3) math/FP order identical to v10 -> absmax bit-identical.
// Kept: decoder rotation (v8), per-gate chains + setprio (v10), log2e
// domain + native exp2 asm (v9), split_tr codegen (NOT asm cvt_pk, m240),
// lgkm-only barrier, XS=40 rows, probe-based pair_fold rows, bias-as-C.

namespace {

typedef __attribute__((ext_vector_type(8))) short bf16x8;
typedef __attribute__((ext_vector_type(4))) float f32x4;
typedef __attribute__((ext_vector_type(2))) unsigned int uint2v;
typedef __attribute__((ext_vector_type(4))) unsigned int uint4v;
typedef __attribute__((ext_vector_type(2))) unsigned short ushort2v;
typedef __attribute__((ext_vector_type(2))) float float2v;

constexpr int T = 512, F = 8, H = 128, G4 = 512, NTH = 512;
constexpr int HS = 136;  // hb row stride in shorts (272B, b128-aligned)
constexpr int XS = 40;   // xp/xq row stride in shorts (80B)
constexpr int CS = 16;   // encoder x chunk length (timesteps)
constexpr float L2E = 1.4426950408889634f;

struct __align__(16) Smem {
  unsigned short hb[2][16][HS];      // rows 0..7 h_hi, 8..15 h_lo; dbuf by parity
  unsigned short xp[2][16][XS];      // decoder feedback y; dbuf by parity
  unsigned short xq[2][CS][16][XS];  // encoder pre-split x chunks; dbuf by chunk
};

__device__ __forceinline__ float rcpf(float v) { return __builtin_amdgcn_rcpf(v); }

// native exp2 (v_exp_f32 IS 2^x); exp2m computes 2^-x via src modifier
__device__ __forceinline__ float exp2p(float x) { float r; asm("v_exp_f32 %0, %1" : "=v"(r) : "v"(x)); return r; }
__device__ __forceinline__ float exp2m(float x) { float r; asm("v_exp_f32_e64 %0, -%1" : "=v"(r) : "v"(x)); return r; }

__device__ __forceinline__ unsigned short bf_rtn(float v) {
  unsigned u = __float_as_uint(v);
  return (unsigned short)((u + 0x7FFFu + ((u >> 16) & 1u)) >> 16);
}
__device__ __forceinline__ void split_tr(float v, unsigned short& hi, unsigned short& lo) {
  unsigned u = __float_as_uint(v);
  hi = (unsigned short)(u >> 16);
  lo = bf_rtn(v - __uint_as_float(u & 0xFFFF0000u));
}

// scaled-domain gates (z' = log2e * z_true):
__device__ __forceinline__ float2v sigm2(float2v z) {        // sigmoid_true
  float2v d = { exp2m(z[0]) + 1.f, exp2m(z[1]) + 1.f };
  return (float2v){ rcpf(d[0]), rcpf(d[1]) };
}
__device__ __forceinline__ float2v gtanh2(float2v z) {       // log2e * tanh_true
  float2v zz = z + z;
  float2v d = { exp2p(zz[0]) + 1.f, exp2p(zz[1]) + 1.f };
  return (float2v){ fmaf(rcpf(d[0]), -2.f * L2E, L2E), fmaf(rcpf(d[1]), -2.f * L2E, L2E) };
}
__device__ __forceinline__ float2v ttanh2(float2v c) {       // tanh_true of scaled c
  float2v cc = c + c;
  float2v d = { exp2p(cc[0]) + 1.f, exp2p(cc[1]) + 1.f };
  return (float2v){ fmaf(rcpf(d[0]), -2.f, 1.f), fmaf(rcpf(d[1]), -2.f, 1.f) };
}

// Pair-fold: one half-wave gets fold32(a)=a[l]+a[l^32], the other fold32(b);
// which half gets which is probed once and baked into r0.
__device__ __forceinline__ float pair_fold(float a, float b) {
  uint2v r = __builtin_amdgcn_permlane32_swap(__float_as_uint(a), __float_as_uint(b), false, false);
  return __uint_as_float(r[0]) + __uint_as_float(r[1]);
}
__device__ __forceinline__ float2v fold4(const f32x4& z4) {
  return (float2v){ pair_fold(z4[0], z4[2]), pair_fold(z4[1], z4[3]) };
}

// Barrier draining only LDS (lgkm); outstanding global ops not drained.
__device__ __forceinline__ void bar_lgkm() {
  __asm__ __volatile__("s_waitcnt lgkmcnt(0)" ::: "memory");
  __builtin_amdgcn_s_barrier();
  __asm__ __volatile__("" ::: "memory");
}

__global__ __launch_bounds__(NTH, 2)
void rae_v11(const float* __restrict__ x,
             const float* __restrict__ Wenc, const float* __restrict__ Uenc, const float* __restrict__ benc,
             const float* __restrict__ Wdec, const float* __restrict__ Udec, const float* __restrict__ bdec,
             const float* __restrict__ Wout, const float* __restrict__ boutg,
             float* __restrict__ out)
{
  __shared__ Smem s;
  const int tid = threadIdx.x, lane = tid & 63, w = tid >> 6;
  const int q = lane >> 4, n = lane & 15;
  const long gb = (long)blockIdx.x * 8;

  {  // vectorized zero of all LDS (zeros double as the K-padding regions)
    uint4v z4 = {0u, 0u, 0u, 0u};
#pragma unroll 4
    for (int i = tid; i < (int)(sizeof(Smem) / 16); i += NTH)
      ((uint4v*)&s)[i] = z4;
  }
  __syncthreads();  // zero pass must complete before any staging

  // encoder x staging: 512 thr = 16 steps x 8 rows x 4 float2.
  const int sfp = tid & 3, srow = (tid >> 2) & 7, sts = tid >> 5;
  const long xsb = (gb + srow) * (long)(T * F) + sts * F + sfp * 2;

  {  // stage chunk 0 (steps 0..15)
    float2v xv0 = *(const float2v*)&x[xsb];
    unsigned short h0s, l0s, h1s, l1s;
    split_tr(xv0[0], h0s, l0s); split_tr(xv0[1], h1s, l1s);
    ushort2v hh = {h0s, h1s}, ll = {l0s, l1s};
    *(ushort2v*)&s.xq[0][sts][srow][sfp * 2] = hh;
    *(ushort2v*)&s.xq[0][sts][srow + 8][sfp * 2] = ll;
    *(ushort2v*)&s.xq[0][sts][srow + 8][8 + sfp * 2] = hh;
  }

  // Wout fragments (UNSCALED): N-cols 0..7 = Wout_hi, 8..15 = Wout_lo
  bf16x8 Bw[4];
#pragma unroll
  for (int kt = 0; kt < 4; ++kt) {
    bf16x8 bw;
#pragma unroll
    for (int j = 0; j < 8; ++j) {
      unsigned short hv, lv; split_tr(Wout[(kt * 32 + q * 8 + j) * F + (n & 7)], hv, lv);
      bw[j] = (short)((n < 8) ? hv : lv);
    }
    Bw[kt] = bw;
  }
  const float boutr = boutg[n & 7];
  float2v cst2 = {0.f, 0.f};  // cell state in log2e-scaled domain
  __syncthreads();

  // Convention probe -> row offset owned by this lane's pair_fold outputs.
  const float probe = pair_fold(0.0f, 1.0f);
  const int r0 = ((lane & 31) >> 4) * 4 + (int)probe;
  const int cc = w * 16 + n;

  bf16x8 A[4], Ax;
  {
    bf16x8 zz = {0, 0, 0, 0, 0, 0, 0, 0};
#pragma unroll
    for (int kt = 0; kt < 4; ++kt) A[kt] = zz;
    Ax = zz;
  }

  bf16x8 B1[5][4];
  f32x4 bias4[4];
  const f32x4 zero4 = {0.f, 0.f, 0.f, 0.f};

  // ---- weight preload (per phase); U/W/bias pre-scaled by log2e ----
  auto preload = [&](const float* U, const float* W, const float* bi) {
#pragma unroll
    for (int kt = 0; kt < 5; ++kt)
#pragma unroll
      for (int g = 0; g < 4; ++g) {
        const int col = g * 128 + w * 16 + n;
        bf16x8 b1;
#pragma unroll
        for (int j = 0; j < 8; ++j) {
          unsigned short v = 0;
          if (kt < 4) {
            v = bf_rtn(L2E * U[(kt * 32 + q * 8 + j) * G4 + col]);
          } else {
            const int kk = q * 8 + j;
            unsigned short hv, lv;
            if (kk < 8)       { split_tr(L2E * W[kk * G4 + col], hv, lv); v = hv; }
            else if (kk < 16) { split_tr(L2E * W[(kk - 8) * G4 + col], hv, lv); v = lv; }
          }
          b1[j] = (short)v;
        }
        B1[kt][g] = b1;
      }
#pragma unroll
    for (int g = 0; g < 4; ++g) {
      const float b = 0.5f * L2E * bi[g * 128 + w * 16 + n];
      bias4[g] = f32x4{b, b, b, b};
    }
  };

  // =================== ENCODER (rotated) ===================
  preload(Uenc, Wenc, benc);

  // prologue: h_{-1}=0 (A zero); px = bias + x_0*W (chunk 0 staged + synced)
  Ax = *(const bf16x8*)&s.xq[0][0][n][q * 8];
  f32x4 px[4];
#pragma unroll
  for (int g = 0; g < 4; ++g)
    px[g] = __builtin_amdgcn_mfma_f32_16x16x32_bf16(Ax, B1[4][g], bias4[g], 0, 0, 0);

  float2v xv = {0.f, 0.f};  // in-flight next-chunk x (held ACROSS steps)

#pragma unroll 2
  for (int t = 0; t < T; ++t) {
    const int pnxt = (t & 1) ^ 1;
    const bool do_load  = (((t + 3) & (CS - 1)) == 0) && (t + 3 < T);
    const bool do_write = (((t + 2) & (CS - 1)) == 0) && (t + 2 < T);
    if (do_load) xv = *(const float2v*)&x[xsb + (long)(t + 3) * F];

    // ---- h-term chains (4 MFMA each), folds interleaved under later chains
    __builtin_amdgcn_s_setprio(1);
    f32x4 zf4 = px[1], zi4 = px[0], zg4 = px[2], zo4 = px[3];
#pragma unroll
    for (int kt = 0; kt < 4; ++kt)
      zf4 = __builtin_amdgcn_mfma_f32_16x16x32_bf16(A[kt], B1[kt][1], zf4, 0, 0, 0);
#pragma unroll
    for (int kt = 0; kt < 4; ++kt)
      zi4 = __builtin_amdgcn_mfma_f32_16x16x32_bf16(A[kt], B1[kt][0], zi4, 0, 0, 0);
    const float2v sf = sigm2(fold4(zf4));   // overlaps g-chain issue
#pragma unroll
    for (int kt = 0; kt < 4; ++kt)
      zg4 = __builtin_amdgcn_mfma_f32_16x16x32_bf16(A[kt], B1[kt][2], zg4, 0, 0, 0);
    const float2v si = sigm2(fold4(zi4));   // overlaps o-chain issue
#pragma unroll
    for (int kt = 0; kt < 4; ++kt)
      zo4 = __builtin_amdgcn_mfma_f32_16x16x32_bf16(A[kt], B1[kt][3], zo4, 0, 0, 0);
    __builtin_amdgcn_s_setprio(0);

    // hoisted: cst2 + tanh(c) ready before the o-tail
    const float2v gg = gtanh2(fold4(zg4));
    cst2 = sf * cst2 + si * gg;
    const float2v tc = ttanh2(cst2);
    const float2v so = sigm2(fold4(zo4));
    const float2v hh = so * tc;
    {
      unsigned short hv0, lv0, hv1, lv1;
      split_tr(hh[0], hv0, lv0); split_tr(hh[1], hv1, lv1);
      s.hb[pnxt][r0][cc]     = hv0;  s.hb[pnxt][r0 + 8][cc] = lv0;
      s.hb[pnxt][r0 + 1][cc] = hv1;  s.hb[pnxt][r0 + 9][cc] = lv1;
    }

    // ---- pre-bar next-step x-term (overlaps the act tail on MFMA pipe) ----
    // safe: chunk for tn was written at latest 2 barriers before first use
    const int tn = t + 1;  // tn==T: stale read + 4 dead MFMA, harmless
    Ax = *(const bf16x8*)&s.xq[(tn >> 4) & 1][tn & (CS - 1)][n][q * 8];
#pragma unroll
    for (int g = 0; g < 4; ++g)
      px[g] = __builtin_amdgcn_mfma_f32_16x16x32_bf16(Ax, B1[4][g], bias4[g], 0, 0, 0);

    if (do_write) {  // writes buffer ((t+2)>>4)&1 != read buffer ((t+1)>>4)&1
      const int cb = ((t + 2) >> 4) & 1;
      unsigned short h0s, l0s, h1s, l1s;
      split_tr(xv[0], h0s, l0s); split_tr(xv[1], h1s, l1s);
      ushort2v hh2 = {h0s, h1s}, ll2 = {l0s, l1s};
      *(ushort2v*)&s.xq[cb][sts][srow][sfp * 2] = hh2;
      *(ushort2v*)&s.xq[cb][sts][srow + 8][sfp * 2] = ll2;
      *(ushort2v*)&s.xq[cb][sts][srow + 8][8 + sfp * 2] = hh2;
    }

    bar_lgkm();

#pragma unroll
    for (int kt = 0; kt < 4; ++kt)
      A[kt] = *(const bf16x8*)&s.hb[pnxt][n][kt * 32 + q * 8];
  }

  // =================== DECODER (rotated) ===================
  preload(Udec, Wdec, bdec);

  if (tid < 64) {  // stage y_{-1} = x[:,T-1,:] into xp[1] (slot (0-1)&1)
    unsigned short hv, lv;
    split_tr(x[(gb + (tid >> 3)) * (long)(T * F) + (T - 1) * F + (tid & 7)], hv, lv);
    s.xp[1][tid >> 3][tid & 7] = hv;
    s.xp[1][(tid >> 3) + 8][tid & 7] = lv;
    s.xp[1][(tid >> 3) + 8][(tid & 7) + 8] = hv;
  }
  __syncthreads();

  // prologue: A still holds h_enc (encoder's final bottom-read of hb[0]).
  f32x4 hacc[4];
#pragma unroll
  for (int g = 0; g < 4; ++g)
    hacc[g] = __builtin_amdgcn_mfma_f32_16x16x32_bf16(A[0], B1[0][g], bias4[g], 0, 0, 0);
#pragma unroll
  for (int kt = 1; kt < 4; ++kt)
#pragma unroll
    for (int g = 0; g < 4; ++g)
      hacc[g] = __builtin_amdgcn_mfma_f32_16x16x32_bf16(A[kt], B1[kt][g], hacc[g], 0, 0, 0);
  Ax = *(const bf16x8*)&s.xp[1][n][q * 8];

  // per-lane output row pointers (rows r0 and r0+1, col n; valid for n<8)
  float* o0 = out + ((gb + r0) * (long)T) * F + n;
  float* o1 = o0 + (long)T * F;

#pragma unroll 2
  for (int t = 0; t < T; ++t) {
    const int wA = (t & 1) ^ 1;  // hb slot for h_t

    // finish LSTM per gate (1 MFMA each); folds interleave under later MFMAs
    f32x4 zf4 = __builtin_amdgcn_mfma_f32_16x16x32_bf16(Ax, B1[4][1], hacc[1], 0, 0, 0);
    f32x4 zi4 = __builtin_amdgcn_mfma_f32_16x16x32_bf16(Ax, B1[4][0], hacc[0], 0, 0, 0);
    const float2v sf = sigm2(fold4(zf4));
    f32x4 zg4 = __builtin_amdgcn_mfma_f32_16x16x32_bf16(Ax, B1[4][2], hacc[2], 0, 0, 0);
    const float2v si = sigm2(fold4(zi4));
    f32x4 zo4 = __builtin_amdgcn_mfma_f32_16x16x32_bf16(Ax, B1[4][3], hacc[3], 0, 0, 0);
    const float2v gg = gtanh2(fold4(zg4));
    cst2 = sf * cst2 + si * gg;
    const float2v tc = ttanh2(cst2);
    const float2v so = sigm2(fold4(zo4));
    const float2v hh = so * tc;
    {
      unsigned short hv0, lv0, hv1, lv1;
      split_tr(hh[0], hv0, lv0); split_tr(hh[1], hv1, lv1);
      s.hb[wA][r0][cc]     = hv0;  s.hb[wA][r0 + 8][cc] = lv0;
      s.hb[wA][r0 + 1][cc] = hv1;  s.hb[wA][r0 + 9][cc] = lv1;
    }

    bar_lgkm();

#pragma unroll
    for (int kt = 0; kt < 4; ++kt)
      A[kt] = *(const bf16x8*)&s.hb[wA][n][kt * 32 + q * 8];

    // dense first (y_t on the feedback critical path) ...
    __builtin_amdgcn_s_setprio(1);
    f32x4 ay = __builtin_amdgcn_mfma_f32_16x16x32_bf16(A[0], Bw[0], zero4, 0, 0, 0);
#pragma unroll
    for (int kt = 1; kt < 4; ++kt)
      ay = __builtin_amdgcn_mfma_f32_16x16x32_bf16(A[kt], Bw[kt], ay, 0, 0, 0);

    // ... then next-step h-partial (16 MFMA, independent of y_t) issues
    // while the y epilogue below runs on VALU.
#pragma unroll
    for (int g = 0; g < 4; ++g)
      hacc[g] = __builtin_amdgcn_mfma_f32_16x16x32_bf16(A[0], B1[0][g], bias4[g], 0, 0, 0);
#pragma unroll
    for (int kt = 1; kt < 4; ++kt)
#pragma unroll
      for (int g = 0; g < 4; ++g)
        hacc[g] = __builtin_amdgcn_mfma_f32_16x16x32_bf16(A[kt], B1[kt][g], hacc[g], 0, 0, 0);
    __builtin_amdgcn_s_setprio(0);

    // y epilogue: fold32 and shfl8 commute -> pf first, single sh8 each
    const float2v sy = { pair_fold(ay[0], ay[2]), pair_fold(ay[1], ay[3]) };
    const float2v sox = { __shfl_xor(sy[0], 8, 64), __shfl_xor(sy[1], 8, 64) };
    const float2v yraw = sy + sox + (float2v){boutr, boutr};
    const float y0 = fmaxf(yraw[0], 0.f), y1 = fmaxf(yraw[1], 0.f);  // rows r0, r0+1
    if (n < 8) {
      if (w == 0) { o0[t * F] = y0; o1[t * F] = y1; }
      unsigned short hv, lv;
      split_tr(y0, hv, lv);
      s.xp[t & 1][r0][n]         = hv;
      s.xp[t & 1][r0 + 8][n]     = lv;
      s.xp[t & 1][r0 + 8][n + 8] = hv;
      split_tr(y1, hv, lv);
      s.xp[t & 1][r0 + 1][n]     = hv;
      s.xp[t & 1][r0 + 9][n]     = lv;
      s.xp[t & 1][r0 + 9][n + 8] = hv;
    }
    // own-wave readback (same-wave DS ordering; proven pattern since v5)
    Ax = *(const bf16x8*)&s.xp[t & 1][n][q * 8];
  }
}

} // namespace

extern "C" void kernel_launch(void* const* d_in, const int* in_sizes, int n_in,
                              void* d_out, int out_size, void* d_ws, size_t ws_size,
                              hipStream_t stream) {
  const float* x    = (const float*)d_in[0];
  const float* Wenc = (const float*)d_in[1];
  const float* Uenc = (const float*)d_in[2];
  const float* benc = (const float*)d_in[3];
  const float* Wdec = (const float*)d_in[4];
  const float* Udec = (const float*)d_in[5];
  const float* bdec = (const float*)d_in[6];
  const float* Wout = (const float*)d_in[7];
  const float* bout = (const float*)d_in[8];
  float* out = (float*)d_out;

  const int Bsz = in_sizes[0] / (T * F);  // 2048
  const int nblocks = Bsz / 8;            // 256
  rae_v11<<<dim3(nblocks), dim3(NTH), 0, stream>>>(
      x, Wenc, Uenc, benc, Wdec, Udec, bdec, Wout, bout, out);
}